// Round 9
// baseline (136.942 us; speedup 1.0000x reference)
//
#include <hip/hip_runtime.h>

#define GX 432
#define GY 496
#define G_TOTAL (GX * GY) /* 214272, GZ=1 */
#define MAX_PTS 32
#define MAX_VOX 20000
#define CAP 64
#define INF_SENTINEL 0x7F7F7F7F
#define PREFIX_K 262144  /* ~133k in-range claims -> ~99k distinct cells >> 20000 */

typedef unsigned long long u64;

// IEEE float32 ops exactly matching the reference:
// c = floor((p - lo)/vs), lo = [0, -39.68, -3], vs = [.16,.16,4].
__device__ __forceinline__ int cell_of(float4 p, bool& ok) {
    float fx = floorf((p.x - 0.0f) / 0.16f);
    float fy = floorf((p.y + 39.68f) / 0.16f);
    float fz = floorf((p.z + 3.0f) / 4.0f);
    int cx = (int)fx, cy = (int)fy, cz = (int)fz;
    ok = (cx >= 0 && cx < GX && cy >= 0 && cy < GY && cz == 0);
    return cy * GX + cx;
}

// Pass 1: 2 points/thread. Fused inits + lin[] store for ALL points + cell
// claim (atomicMin) only for the prefix i < K. dcount (distinct cells claimed)
// computed from atomicMin return values: old==INF happens exactly once per
// cell. dcount starts at INF_SENTINEL (covered by the 0x7F memset).
__global__ __launch_bounds__(256) void pass1(const float4* __restrict__ pts,
                                             int* __restrict__ lin,
                                             int* __restrict__ first,
                                             u64* __restrict__ isFirst64,
                                             int* __restrict__ vcount,
                                             int* __restrict__ cellOfRank,
                                             int* __restrict__ rank,
                                             int* __restrict__ dcount,
                                             int W, int K, int n) {
    int t = blockIdx.x * 256 + threadIdx.x;
    // fused inits (consumed only by LATER kernels)
    if (t < W * 8) isFirst64[t] = 0ull;  // zero W*64 bytes of isFirst
    if (t < MAX_VOX) { vcount[t] = -1; cellOfRank[t] = -1; }
    if (t < G_TOTAL) rank[t] = INF_SENTINEL;  // cells never ranked -> huge
    int i0 = 2 * t;
    int claims = 0;
    if (i0 < n) {
        float4 p0 = pts[i0];
        bool ok0;
        int c0 = cell_of(p0, ok0);
        int l0 = ok0 ? c0 : -1;
        int l1 = -1;
        if (i0 + 1 < n) {
            float4 p1 = pts[i0 + 1];
            bool ok1;
            int c1 = cell_of(p1, ok1);
            l1 = ok1 ? c1 : -1;
            if (ok1 && i0 + 1 < K)
                claims += (atomicMin(&first[c1], i0 + 1) == INF_SENTINEL);
        }
        if (ok0 && i0 < K)
            claims += (atomicMin(&first[c0], i0) == INF_SENTINEL);
        *(int2*)(lin + i0) = make_int2(l0, l1);  // i0 even -> 8B aligned
    }
    // wave-aggregate distinct-claim count
    for (int d = 32; d >= 1; d >>= 1) claims += __shfl_down(claims, d, 64);
    if ((threadIdx.x & 63) == 0 && claims > 0) atomicAdd(dcount, claims);
}

// Guard: if the prefix produced fewer than MAX_VOX distinct cells, the prefix
// bound is insufficient — claim the remaining points too (filtered atomicMin;
// predicate proven exact in round 7). No-op for this input distribution.
__global__ __launch_bounds__(256) void guard(const float4* __restrict__ pts,
                                             int* __restrict__ first,
                                             const int* __restrict__ dcount,
                                             int K, int n) {
    if (*(volatile int*)dcount - INF_SENTINEL >= MAX_VOX) return;
    for (int i = K + blockIdx.x * 256 + threadIdx.x; i < n;
         i += gridDim.x * 256) {
        float4 p = pts[i];
        bool ok;
        int c = cell_of(p, ok);
        if (ok && first[c] > i) atomicMin(&first[c], i);
    }
}

// Mark first-point bytes. Distinct cells have distinct first indices, so a
// plain byte store is race-free (byte stores are byte-granular in HW).
__global__ __launch_bounds__(256) void markFirst(const int* __restrict__ first,
                                                 unsigned char* __restrict__ isFirst,
                                                 int n) {
    int c = blockIdx.x * 256 + threadIdx.x;
    if (c >= G_TOTAL) return;
    int f = first[c];
    if (f >= 0 && f < n) isFirst[f] = 1;
}

// Fused scan (last-block pattern): pack isFirst bytes -> bits[], write
// per-word intra-block exclusive prefix (wordLocal) + per-block sums; the
// LAST block to finish exclusive-scans the block sums in place and writes
// num_voxels. ticket starts at INF_SENTINEL (0x7F memset).
__global__ __launch_bounds__(256) void kScan(const u64* __restrict__ isFirst64,
                                             u64* __restrict__ bits,
                                             unsigned* __restrict__ wordLocal,
                                             int* __restrict__ sums,
                                             int* __restrict__ ticket,
                                             float* __restrict__ nvOut, int W,
                                             int nbW) {
    __shared__ int wsum[4], wexc[4];
    __shared__ int lastFlag;
    int t = threadIdx.x;
    int wi = blockIdx.x * 256 + t;
    u64 mask = 0;
    if (wi < W) {
        const u64* src = isFirst64 + (size_t)wi * 8;
#pragma unroll
        for (int j = 0; j < 8; j++) {
            u64 chunk = src[j];  // 8 bytes, each 0 or 1
            u64 m8 = (chunk * 0x0102040810204080ull) >> 56;  // gather LSBs
            mask |= m8 << (8 * j);
        }
        bits[wi] = mask;
    }
    int v = __popcll(mask);
    int lane = t & 63, w = t >> 6;
    int x = v;
    for (int d = 1; d < 64; d <<= 1) {
        int y = __shfl_up(x, d, 64);
        if (lane >= d) x += y;
    }
    if (lane == 63) wsum[w] = x;
    __syncthreads();
    if (t == 0) {
        int a = 0;
        for (int j = 0; j < 4; j++) { wexc[j] = a; a += wsum[j]; }
        sums[blockIdx.x] = a;
        __threadfence();
        int old = atomicAdd(ticket, 1);
        lastFlag = (old - INF_SENTINEL == nbW - 1);
    }
    __syncthreads();
    if (wi < W) wordLocal[wi] = (unsigned)(wexc[w] + x - v);
    if (!lastFlag) return;
    // ---- last block: exclusive-scan sums[0..nbW) (nbW <= 128) ----
    int sv = 0;
    if (t < nbW)
        sv = __hip_atomic_load(&sums[t], __ATOMIC_RELAXED,
                               __HIP_MEMORY_SCOPE_AGENT);
    int sx = sv;
    for (int d = 1; d < 64; d <<= 1) {
        int y = __shfl_up(sx, d, 64);
        if (lane >= d) sx += y;
    }
    __syncthreads();  // reuse wsum safely
    if (lane == 63) wsum[w] = sx;
    __syncthreads();
    if (t == 0) {
        int a = 0;
        for (int j = 0; j < 2; j++) { wexc[j] = a; a += wsum[j]; }
        nvOut[0] = (float)(a < MAX_VOX ? a : MAX_VOX);
    }
    __syncthreads();
    if (t < nbW) sums[t] = wexc[w] + sx - sv;
}

// Rank cells: O(1) per cell — block base + intra-block word prefix + bit pop.
__global__ __launch_bounds__(256) void rankCells(const int* __restrict__ first,
                                                 const u64* __restrict__ bits,
                                                 const unsigned* __restrict__ wordLocal,
                                                 const int* __restrict__ sumsExcl,
                                                 int* __restrict__ rank,
                                                 int* __restrict__ cellOfRank, int n) {
    int c = blockIdx.x * 256 + threadIdx.x;
    if (c >= G_TOTAL) return;
    int f = first[c];
    if (f < 0 || f >= n) return;
    int wf = f >> 6;
    int b = f & 63;
    u64 lowmask = (b == 0) ? 0ull : ((~0ull) >> (64 - b));
    int vr = sumsExcl[wf >> 8] + (int)wordLocal[wf] + __popcll(bits[wf] & lowmask);
    rank[c] = vr;
    if (vr < MAX_VOX) cellOfRank[vr] = c;
}

// Pass 5: 4 points/thread. Append point indices into kept voxels' lists.
// vcount starts at -1; atomicAdd returns old, pos = old+1. rank[] is INF for
// cells never ranked, filtering all points of non-kept cells (~91% skip).
__global__ __launch_bounds__(256) void pass5(const int4* __restrict__ lin4,
                                             const int* __restrict__ rank,
                                             int* __restrict__ vcount,
                                             int* __restrict__ list, int n) {
    int t = blockIdx.x * 256 + threadIdx.x;
    int i0 = 4 * t;
    if (i0 >= n) return;
    int4 L = lin4[t];
    int cs[4] = {L.x, L.y, L.z, L.w};
#pragma unroll
    for (int k = 0; k < 4; k++) {
        int i = i0 + k;
        if (i >= n) break;
        int c = cs[k];
        if (c < 0) continue;
        int vr = rank[c];
        if (vr >= MAX_VOX) continue;
        int pos = atomicAdd(&vcount[vr], 1) + 1;
        if (pos < CAP) list[vr * CAP + pos] = i;
    }
}

// Pass F: 4 voxels per 256-thread block (one wave each). Counting-sort the
// collected indices (LDS broadcast reads), write all 32 slots + num_points
// + coors (so no d_out pre-memset is needed).
__global__ __launch_bounds__(256) void passF(const float4* __restrict__ pts,
                                             const int* __restrict__ vcount,
                                             const int* __restrict__ cellOfRank,
                                             const int* __restrict__ list,
                                             float4* __restrict__ voxOut,
                                             float* __restrict__ coorsOut,
                                             float* __restrict__ npOut) {
    __shared__ int s[4][CAP];
    __shared__ int slotPt[4][MAX_PTS];
    int w = threadIdx.x >> 6, lane = threadIdx.x & 63;
    int v = blockIdx.x * 4 + w;
    int cnt = vcount[v] + 1;
    int m = cnt < CAP ? cnt : CAP;
    s[w][lane] = (lane < m) ? list[v * CAP + lane] : 0x7FFFFFFF;
    if (lane < MAX_PTS) slotPt[w][lane] = -1;
    __syncthreads();
    int my = s[w][lane];
    int r = 0;
#pragma unroll
    for (int j = 0; j < CAP; j++) r += (s[w][j] < my) ? 1 : 0;  // broadcast
    if (lane < m && r < MAX_PTS) slotPt[w][r] = my;
    __syncthreads();
    if (lane < MAX_PTS) {
        int p = slotPt[w][lane];
        float4 val = make_float4(0.f, 0.f, 0.f, 0.f);
        if (p >= 0) val = pts[p];
        voxOut[(size_t)v * MAX_PTS + lane] = val;
    }
    if (lane == 0) {
        npOut[v] = (float)(cnt < MAX_PTS ? cnt : MAX_PTS);
        int cell = cellOfRank[v];
        if (cell < 0) {
            coorsOut[3 * v + 0] = -1.0f;
            coorsOut[3 * v + 1] = -1.0f;
            coorsOut[3 * v + 2] = -1.0f;
        } else {
            coorsOut[3 * v + 0] = 0.0f;  // cz (GZ==1)
            coorsOut[3 * v + 1] = (float)(cell / GX);
            coorsOut[3 * v + 2] = (float)(cell % GX);
        }
    }
}

extern "C" void kernel_launch(void* const* d_in, const int* in_sizes, int n_in,
                              void* d_out, int out_size, void* d_ws, size_t ws_size,
                              hipStream_t stream) {
    const float4* pts = (const float4*)d_in[0];
    int n = in_sizes[0] / 4;  // 2,000,000
    int W = (n + 63) >> 6;    // 31250 bitmap words
    int K = PREFIX_K < n ? PREFIX_K : n;

    char* ws = (char*)d_ws;
    size_t off = 0;
    auto alloc = [&](size_t bytes) -> void* {
        void* p = (void*)(ws + off);
        off = (off + bytes + 255) & ~(size_t)255;
        return p;
    };
    int* first = (int*)alloc((size_t)(G_TOTAL + 8) * 4);  // + dcount + ticket
    int* dcount = first + G_TOTAL;
    int* ticket = first + G_TOTAL + 1;
    int* lin = (int*)alloc((size_t)n * 4);
    u64* isFirst64 = (u64*)alloc((size_t)W * 8 * 8);      // W*64 bytes
    u64* bits = (u64*)alloc((size_t)W * 8);
    unsigned* wordLocal = (unsigned*)alloc((size_t)W * 4);
    int* sums = (int*)alloc(128 * 4);
    int* rank = (int*)alloc((size_t)G_TOTAL * 4);
    int* vcount = (int*)alloc((size_t)MAX_VOX * 4);
    int* cellOfRank = (int*)alloc((size_t)MAX_VOX * 4);
    int* list = (int*)alloc((size_t)MAX_VOX * CAP * 4);
    (void)ws_size;
    (void)n_in;
    (void)out_size;

    float* out = (float*)d_out;
    float4* voxOut = (float4*)out;                          // 20000*32*4
    float* coorsOut = out + (size_t)MAX_VOX * MAX_PTS * 4;  // 20000*3
    float* npOut = coorsOut + (size_t)MAX_VOX * 3;          // 20000
    float* nvOut = npOut + MAX_VOX;                         // 1

    // first/dcount/ticket all -> 0x7F7F7F7F
    hipMemsetAsync(first, 0x7F, (size_t)(G_TOTAL + 8) * 4, stream);

    int nbP2 = (n + 511) / 512;       // 3907  (2 pts/thread)
    int nbC = (G_TOTAL + 255) / 256;  // 837
    int nbW = (W + 255) / 256;        // 123
    int nbP4 = (n + 1023) / 1024;     // 1954  (4 pts/thread)

    pass1<<<nbP2, 256, 0, stream>>>(pts, lin, first, isFirst64, vcount,
                                    cellOfRank, rank, dcount, W, K, n);
    guard<<<256, 256, 0, stream>>>(pts, first, dcount, K, n);
    markFirst<<<nbC, 256, 0, stream>>>(first, (unsigned char*)isFirst64, n);
    kScan<<<nbW, 256, 0, stream>>>(isFirst64, bits, wordLocal, sums, ticket,
                                   nvOut, W, nbW);
    rankCells<<<nbC, 256, 0, stream>>>(first, bits, wordLocal, sums, rank,
                                       cellOfRank, n);
    pass5<<<nbP4, 256, 0, stream>>>((const int4*)lin, rank, vcount, list, n);
    passF<<<MAX_VOX / 4, 256, 0, stream>>>(pts, vcount, cellOfRank, list,
                                           voxOut, coorsOut, npOut);
}